// Round 1
// baseline (760.658 us; speedup 1.0000x reference)
//
#include <hip/hip_runtime.h>
#include <math.h>

constexpr int N_ = 1024;
constexpr int H_ = 128;
constexpr int D_ = 256;
constexpr int L_ = 3;
constexpr float EPS_ = 1e-5f;

__device__ __forceinline__ float siluf(float v) {
    return v / (1.0f + __expf(-v));
}

// ---------------- embedding gather ----------------
__global__ void k_embed(const int* __restrict__ an, const float* __restrict__ emb,
                        float* __restrict__ x) {
    int idx = blockIdx.x * 256 + threadIdx.x;
    int i = idx >> 7, h = idx & (H_ - 1);
    x[idx] = emb[an[i] * H_ + h];
}

// ---------------- pre = x@Wi + msg_b, prj = x@Wj ----------------
__global__ void k_gemm_pp(const float* __restrict__ x, const float* __restrict__ W,
                          const float* __restrict__ b, float* __restrict__ preb,
                          float* __restrict__ prj) {
    int i = blockIdx.x;
    int t = threadIdx.x;               // 256 threads
    __shared__ float xr[H_];
    if (t < H_) xr[t] = x[i * H_ + t];
    __syncthreads();
    int h = t & (H_ - 1);
    int off = (t >= H_) ? H_ : 0;      // first half: Wi, second half: Wj
    float s = 0.f;
#pragma unroll 8
    for (int k = 0; k < H_; ++k)
        s = fmaf(xr[k], W[(off + k) * H_ + h], s);
    if (t >= H_) prj[i * H_ + h] = s;
    else         preb[i * H_ + h] = s + b[h];
}

// ---------------- the big pairwise kernel ----------------
// block = row i, 256 threads = 4 waves; each 16-lane group owns one pair (i,j);
// each lane owns 8 strided channels (c = q + 16k).
__global__ __launch_bounds__(256) void k_pair(
    const float* __restrict__ pos, const float* __restrict__ preb,
    const float* __restrict__ prj,
    const float* __restrict__ deW, const float* __restrict__ deb,
    const float* __restrict__ deg, const float* __restrict__ debe,
    const float* __restrict__ mgp, const float* __restrict__ mbep,
    float* __restrict__ msum) {
    const int i = blockIdx.x;
    const int tid = threadIdx.x;
    const int w = tid >> 6;
    const int lane = tid & 63;
    const int g = lane >> 4;
    const int q = lane & 15;
    const int p = w * 4 + g;           // 0..15: pair slot within block

    float W0[8], W1[8], W2[8], dbv[8], dgv[8], dbev[8], pbv[8], mgv[8], mbev[8], acc[8];
#pragma unroll
    for (int k = 0; k < 8; ++k) {
        int c = q + 16 * k;
        W0[k] = deW[c]; W1[k] = deW[H_ + c]; W2[k] = deW[2 * H_ + c];
        dbv[k] = deb[c]; dgv[k] = deg[c]; dbev[k] = debe[c];
        pbv[k] = preb[i * H_ + c];
        mgv[k] = mgp[c]; mbev[k] = mbep[c];
        acc[k] = 0.f;
    }
    const float pix = pos[3 * i], piy = pos[3 * i + 1], piz = pos[3 * i + 2];

    for (int jt = 0; jt < N_; jt += 16) {
        const int j = jt + p;
        float dx = pix - pos[3 * j];
        float dy = piy - pos[3 * j + 1];
        float dz = piz - pos[3 * j + 2];
        float sq = fmaf(dx, dx, fmaf(dy, dy, dz * dz));
        float d = sqrtf(sq);           // sq==0 -> d==0, matches reference
        float s0 = __expf(-d);
        float s1 = sqrtf(s0);          // exp(-d/2)
        float s2 = sqrtf(s1);          // exp(-d/4)

        // ---- ew = LN(silu(scales @ de_W + de_b)) * de_g + de_be ----
        float e[8];
        float sum = 0.f, ssq = 0.f;
#pragma unroll
        for (int k = 0; k < 8; ++k) {
            float v = fmaf(s0, W0[k], fmaf(s1, W1[k], fmaf(s2, W2[k], dbv[k])));
            v = siluf(v);
            e[k] = v; sum += v; ssq = fmaf(v, v, ssq);
        }
#pragma unroll
        for (int mask = 1; mask < 16; mask <<= 1) {
            sum += __shfl_xor(sum, mask);
            ssq += __shfl_xor(ssq, mask);
        }
        float mu = sum * (1.f / H_);
        float var = fmaf(ssq, 1.f / H_, -mu * mu);
        float rstd = rsqrtf(var + EPS_);
#pragma unroll
        for (int k = 0; k < 8; ++k)
            e[k] = fmaf((e[k] - mu) * rstd, dgv[k], dbev[k]);

        // ---- m = LN(silu(pre_i + prj_j + msg_b)) * msg_g + msg_be ----
        float tm[8];
        sum = 0.f; ssq = 0.f;
        const float* prow = prj + j * H_;
#pragma unroll
        for (int k = 0; k < 8; ++k) {
            float v = pbv[k] + prow[q + 16 * k];
            v = siluf(v);
            tm[k] = v; sum += v; ssq = fmaf(v, v, ssq);
        }
#pragma unroll
        for (int mask = 1; mask < 16; mask <<= 1) {
            sum += __shfl_xor(sum, mask);
            ssq += __shfl_xor(ssq, mask);
        }
        mu = sum * (1.f / H_);
        var = fmaf(ssq, 1.f / H_, -mu * mu);
        rstd = rsqrtf(var + EPS_);
#pragma unroll
        for (int k = 0; k < 8; ++k)
            acc[k] = fmaf(fmaf((tm[k] - mu) * rstd, mgv[k], mbev[k]), e[k], acc[k]);
    }

    // ---- combine the 16 pair-slots' partial sums ----
    __shared__ float red[16][H_];
#pragma unroll
    for (int k = 0; k < 8; ++k) red[p][q + 16 * k] = acc[k];
    __syncthreads();
    if (tid < H_) {
        float s = 0.f;
#pragma unroll
        for (int pp = 0; pp < 16; ++pp) s += red[pp][tid];
        msum[i * H_ + tid] = s;
    }
}

// ---------------- x += LN(silu([x,msum]@upd_W + upd_b)); lmean += x ----------------
__global__ void k_update(const float* __restrict__ x_in, const float* __restrict__ msum,
                         const float* __restrict__ uW, const float* __restrict__ ub,
                         const float* __restrict__ ug, const float* __restrict__ ube,
                         float* __restrict__ x_out, float* __restrict__ lmean) {
    int i = blockIdx.x;
    int h = threadIdx.x;               // 128 threads
    __shared__ float u[2 * H_];
    u[h] = x_in[i * H_ + h];
    u[H_ + h] = msum[i * H_ + h];
    __syncthreads();
    float s = ub[h];
#pragma unroll 8
    for (int k = 0; k < 2 * H_; ++k)
        s = fmaf(u[k], uW[k * H_ + h], s);
    float v = siluf(s);
    float sum = v, ssq = v * v;
#pragma unroll
    for (int mask = 1; mask < 64; mask <<= 1) {
        sum += __shfl_xor(sum, mask);
        ssq += __shfl_xor(ssq, mask);
    }
    __shared__ float r2[2][2];
    int wv = h >> 6;
    if ((h & 63) == 0) { r2[wv][0] = sum; r2[wv][1] = ssq; }
    __syncthreads();
    sum = r2[0][0] + r2[1][0];
    ssq = r2[0][1] + r2[1][1];
    float mu = sum * (1.f / H_);
    float var = fmaf(ssq, 1.f / H_, -mu * mu);
    float rstd = rsqrtf(var + EPS_);
    float xn = u[h] + fmaf((v - mu) * rstd, ug[h], ube[h]);
    x_out[i * H_ + h] = xn;
    atomicAdd(&lmean[h], xn);
}

// ---------------- out = LN(combined @ fp_W + fp_b) ----------------
__global__ void k_final(const float* __restrict__ lmean, const float* __restrict__ fpW,
                        const float* __restrict__ fpb, const float* __restrict__ fpg,
                        const float* __restrict__ fpbe, float* __restrict__ out) {
    int t = threadIdx.x;               // 256 threads
    __shared__ float comb[L_ * H_];    // 384
    comb[t] = lmean[t] * (1.f / N_);
    if (t < L_ * H_ - D_) comb[D_ + t] = lmean[D_ + t] * (1.f / N_);
    __syncthreads();
    float s = fpb[t];
#pragma unroll 8
    for (int k = 0; k < L_ * H_; ++k)
        s = fmaf(comb[k], fpW[k * D_ + t], s);
    float sum = s, ssq = s * s;
#pragma unroll
    for (int mask = 1; mask < 64; mask <<= 1) {
        sum += __shfl_xor(sum, mask);
        ssq += __shfl_xor(ssq, mask);
    }
    __shared__ float r4[4][2];
    int wv = t >> 6;
    if ((t & 63) == 0) { r4[wv][0] = sum; r4[wv][1] = ssq; }
    __syncthreads();
    sum = r4[0][0] + r4[1][0] + r4[2][0] + r4[3][0];
    ssq = r4[0][1] + r4[1][1] + r4[2][1] + r4[3][1];
    float mu = sum * (1.f / D_);
    float var = fmaf(ssq, 1.f / D_, -mu * mu);
    float rstd = rsqrtf(var + EPS_);
    out[t] = fmaf((s - mu) * rstd, fpg[t], fpbe[t]);
}

extern "C" void kernel_launch(void* const* d_in, const int* in_sizes, int n_in,
                              void* d_out, int out_size, void* d_ws, size_t ws_size,
                              hipStream_t stream) {
    const int*   an    = (const int*)d_in[0];
    const float* pos   = (const float*)d_in[1];
    const float* emb   = (const float*)d_in[2];
    const float* deW   = (const float*)d_in[3];
    const float* deb   = (const float*)d_in[4];
    const float* deg   = (const float*)d_in[5];
    const float* debe  = (const float*)d_in[6];
    const float* msgW  = (const float*)d_in[7];
    const float* msgb  = (const float*)d_in[8];
    const float* msgg  = (const float*)d_in[9];
    const float* msgbe = (const float*)d_in[10];
    const float* updW  = (const float*)d_in[11];
    const float* updb  = (const float*)d_in[12];
    const float* updg  = (const float*)d_in[13];
    const float* updbe = (const float*)d_in[14];
    const float* fpW   = (const float*)d_in[15];
    const float* fpb   = (const float*)d_in[16];
    const float* fpg   = (const float*)d_in[17];
    const float* fpbe  = (const float*)d_in[18];
    float* out = (float*)d_out;

    float* ws    = (float*)d_ws;
    float* x     = ws;                 // N*H
    float* preb  = x    + N_ * H_;     // N*H
    float* prj   = preb + N_ * H_;     // N*H
    float* msum  = prj  + N_ * H_;     // N*H
    float* lmean = msum + N_ * H_;     // L*H

    hipMemsetAsync(lmean, 0, L_ * H_ * sizeof(float), stream);
    k_embed<<<N_ * H_ / 256, 256, 0, stream>>>(an, emb, x);
    for (int lvl = 0; lvl < L_; ++lvl) {
        k_gemm_pp<<<N_, 256, 0, stream>>>(x, msgW + lvl * 2 * H_ * H_, msgb + lvl * H_,
                                          preb, prj);
        k_pair<<<N_, 256, 0, stream>>>(pos, preb, prj, deW, deb, deg, debe,
                                       msgg + lvl * H_, msgbe + lvl * H_, msum);
        k_update<<<N_, H_, 0, stream>>>(x, msum, updW + lvl * 2 * H_ * H_, updb + lvl * H_,
                                        updg + lvl * H_, updbe + lvl * H_, x,
                                        lmean + lvl * H_);
    }
    k_final<<<1, D_, 0, stream>>>(lmean, fpW, fpb, fpg, fpbe, out);
}

// Round 2
// 439.608 us; speedup vs baseline: 1.7303x; 1.7303x over previous
//
#include <hip/hip_runtime.h>
#include <math.h>

constexpr int N_ = 1024;
constexpr int H_ = 128;
constexpr int D_ = 256;
constexpr int L_ = 3;
constexpr float EPS_ = 1e-5f;
constexpr float LOG2E_ = 1.44269504f;

__device__ __forceinline__ float fsig(float v) {            // sigmoid(v), ~1ulp
    float e = __builtin_amdgcn_exp2f(v * -LOG2E_);          // exp(-v)
    return __builtin_amdgcn_rcpf(1.0f + e);
}

// butterfly-equivalent reduction over each 16-lane row via DPP row_ror
template <int CTRL>
__device__ __forceinline__ float rowadd(float x) {
    int y = __builtin_amdgcn_update_dpp(0, __float_as_int(x), CTRL, 0xF, 0xF, true);
    return x + __int_as_float(y);
}
__device__ __forceinline__ float rowreduce16(float x) {
    x = rowadd<0x128>(x);   // row_ror:8
    x = rowadd<0x124>(x);   // row_ror:4
    x = rowadd<0x122>(x);   // row_ror:2
    x = rowadd<0x121>(x);   // row_ror:1
    return x;
}

#define LD8(dst, src)                                                     \
    {                                                                     \
        float4 t0_ = *(const float4*)(src);                               \
        float4 t1_ = *(const float4*)((src) + 4);                         \
        dst[0] = t0_.x; dst[1] = t0_.y; dst[2] = t0_.z; dst[3] = t0_.w;   \
        dst[4] = t1_.x; dst[5] = t1_.y; dst[6] = t1_.z; dst[7] = t1_.w;   \
    }

// ---------------- embedding gather ----------------
__global__ void k_embed(const int* __restrict__ an, const float* __restrict__ emb,
                        float* __restrict__ x) {
    int idx = blockIdx.x * 256 + threadIdx.x;
    int i = idx >> 7, h = idx & (H_ - 1);
    x[idx] = emb[an[i] * H_ + h];
}

// ---------------- pre = x@Wi + msg_b, prj = x@Wj ----------------
__global__ void k_gemm_pp(const float* __restrict__ x, const float* __restrict__ W,
                          const float* __restrict__ b, float* __restrict__ preb,
                          float* __restrict__ prj) {
    int i = blockIdx.x;
    int t = threadIdx.x;               // 256 threads
    __shared__ float xr[H_];
    if (t < H_) xr[t] = x[i * H_ + t];
    __syncthreads();
    int h = t & (H_ - 1);
    int off = (t >= H_) ? H_ : 0;      // first half: Wi, second half: Wj
    float s = 0.f;
#pragma unroll 4
    for (int k = 0; k < H_; k += 4) {
        float4 xv = *(const float4*)&xr[k];
        s = fmaf(xv.x, W[(off + k) * H_ + h], s);
        s = fmaf(xv.y, W[(off + k + 1) * H_ + h], s);
        s = fmaf(xv.z, W[(off + k + 2) * H_ + h], s);
        s = fmaf(xv.w, W[(off + k + 3) * H_ + h], s);
    }
    if (t >= H_) prj[i * H_ + h] = s;
    else         preb[i * H_ + h] = s + b[h];
}

// ---------------- the big pairwise kernel ----------------
// block = row i, 256 threads = 4 waves; each 16-lane row owns one pair (i,j);
// lane q (0..15 in row) owns 8 CONTIGUOUS channels [8q, 8q+8).
__global__ __launch_bounds__(256, 4) void k_pair(
    const float* __restrict__ pos, const float* __restrict__ preb,
    const float* __restrict__ prj,
    const float* __restrict__ deW, const float* __restrict__ deb,
    const float* __restrict__ deg, const float* __restrict__ debe,
    const float* __restrict__ mgp, const float* __restrict__ mbep,
    float* __restrict__ msum) {
    const int i = blockIdx.x;
    const int tid = threadIdx.x;
    const int w = tid >> 6;
    const int lane = tid & 63;
    const int g = lane >> 4;
    const int q = lane & 15;
    const int p = w * 4 + g;           // 0..15: pair slot within block
    const int cb = q * 8;              // channel base

    float W0[8], W1[8], W2[8], dbv[8], dgv[8], dbev[8], pbv[8], mgv[8], mbev[8], acc[8];
    LD8(W0, deW + cb);
    LD8(W1, deW + H_ + cb);
    LD8(W2, deW + 2 * H_ + cb);
    LD8(dbv, deb + cb);
    LD8(dgv, deg + cb);
    LD8(dbev, debe + cb);
    LD8(pbv, preb + i * H_ + cb);
    LD8(mgv, mgp + cb);
    LD8(mbev, mbep + cb);
#pragma unroll
    for (int k = 0; k < 8; ++k) acc[k] = 0.f;

    const float pix = pos[3 * i], piy = pos[3 * i + 1], piz = pos[3 * i + 2];

    for (int jt = 0; jt < N_; jt += 16) {
        const int j = jt + p;
        const float* pj = pos + 3 * j;
        float dx = pix - pj[0];
        float dy = piy - pj[1];
        float dz = piz - pj[2];
        float sq = fmaf(dx, dx, fmaf(dy, dy, dz * dz));
        float d = __builtin_amdgcn_sqrtf(sq);              // sq==0 -> 0, matches ref
        float s0 = __builtin_amdgcn_exp2f(d * -LOG2E_);    // exp(-d)
        float s1 = __builtin_amdgcn_sqrtf(s0);             // exp(-d/2)
        float s2 = __builtin_amdgcn_sqrtf(s1);             // exp(-d/4)

        // ---- ew = LN(silu(scales @ de_W + de_b)) * de_g + de_be ----
        float e[8];
        float sum = 0.f, ssq = 0.f;
#pragma unroll
        for (int k = 0; k < 8; ++k) {
            float v = fmaf(s0, W0[k], fmaf(s1, W1[k], fmaf(s2, W2[k], dbv[k])));
            v *= fsig(v);
            e[k] = v; sum += v; ssq = fmaf(v, v, ssq);
        }
        sum = rowreduce16(sum);
        ssq = rowreduce16(ssq);
        float mu = sum * (1.f / H_);
        float var = fmaf(ssq, 1.f / H_, -mu * mu);
        float rstd = __builtin_amdgcn_rsqf(var + EPS_);
        float c0 = -mu * rstd;
#pragma unroll
        for (int k = 0; k < 8; ++k)
            e[k] = fmaf(fmaf(e[k], rstd, c0), dgv[k], dbev[k]);

        // ---- m = LN(silu(pre_i + prj_j + msg_b)) * msg_g + msg_be; acc += m*ew ----
        const float* prow = prj + j * H_ + cb;
        float4 pa = *(const float4*)prow;
        float4 pb4 = *(const float4*)(prow + 4);
        float tm[8] = {pa.x, pa.y, pa.z, pa.w, pb4.x, pb4.y, pb4.z, pb4.w};
        sum = 0.f; ssq = 0.f;
#pragma unroll
        for (int k = 0; k < 8; ++k) {
            float v = pbv[k] + tm[k];
            v *= fsig(v);
            tm[k] = v; sum += v; ssq = fmaf(v, v, ssq);
        }
        sum = rowreduce16(sum);
        ssq = rowreduce16(ssq);
        mu = sum * (1.f / H_);
        var = fmaf(ssq, 1.f / H_, -mu * mu);
        rstd = __builtin_amdgcn_rsqf(var + EPS_);
        float c1 = -mu * rstd;
#pragma unroll
        for (int k = 0; k < 8; ++k)
            acc[k] = fmaf(fmaf(fmaf(tm[k], rstd, c1), mgv[k], mbev[k]), e[k], acc[k]);
    }

    // ---- combine the 16 pair-slots' partial sums ----
    __shared__ float red[16][H_];
    *(float4*)&red[p][cb] = make_float4(acc[0], acc[1], acc[2], acc[3]);
    *(float4*)&red[p][cb + 4] = make_float4(acc[4], acc[5], acc[6], acc[7]);
    __syncthreads();
    if (tid < H_) {
        float s = 0.f;
#pragma unroll
        for (int pp = 0; pp < 16; ++pp) s += red[pp][tid];
        msum[i * H_ + tid] = s;
    }
}

// ---------------- x += LN(silu([x,msum]@upd_W + upd_b)); lmean += x ----------------
__global__ void k_update(const float* __restrict__ x_in, const float* __restrict__ msum,
                         const float* __restrict__ uW, const float* __restrict__ ub,
                         const float* __restrict__ ug, const float* __restrict__ ube,
                         float* __restrict__ x_out, float* __restrict__ lmean) {
    int i = blockIdx.x;
    int h = threadIdx.x;               // 128 threads
    __shared__ float u[2 * H_];
    u[h] = x_in[i * H_ + h];
    u[H_ + h] = msum[i * H_ + h];
    __syncthreads();
    float s = ub[h];
#pragma unroll 4
    for (int k = 0; k < 2 * H_; k += 4) {
        float4 uv = *(const float4*)&u[k];
        s = fmaf(uv.x, uW[k * H_ + h], s);
        s = fmaf(uv.y, uW[(k + 1) * H_ + h], s);
        s = fmaf(uv.z, uW[(k + 2) * H_ + h], s);
        s = fmaf(uv.w, uW[(k + 3) * H_ + h], s);
    }
    float v = s * fsig(s);
    float sum = v, ssq = v * v;
#pragma unroll
    for (int mask = 1; mask < 64; mask <<= 1) {
        sum += __shfl_xor(sum, mask);
        ssq += __shfl_xor(ssq, mask);
    }
    __shared__ float r2[2][2];
    int wv = h >> 6;
    if ((h & 63) == 0) { r2[wv][0] = sum; r2[wv][1] = ssq; }
    __syncthreads();
    sum = r2[0][0] + r2[1][0];
    ssq = r2[0][1] + r2[1][1];
    float mu = sum * (1.f / H_);
    float var = fmaf(ssq, 1.f / H_, -mu * mu);
    float rstd = rsqrtf(var + EPS_);
    float xn = u[h] + fmaf((v - mu) * rstd, ug[h], ube[h]);
    x_out[i * H_ + h] = xn;
    atomicAdd(&lmean[h], xn);
}

// ---------------- out = LN(combined @ fp_W + fp_b) ----------------
__global__ void k_final(const float* __restrict__ lmean, const float* __restrict__ fpW,
                        const float* __restrict__ fpb, const float* __restrict__ fpg,
                        const float* __restrict__ fpbe, float* __restrict__ out) {
    int t = threadIdx.x;               // 256 threads
    __shared__ float comb[L_ * H_];    // 384
    comb[t] = lmean[t] * (1.f / N_);
    if (t < L_ * H_ - D_) comb[D_ + t] = lmean[D_ + t] * (1.f / N_);
    __syncthreads();
    float s = fpb[t];
#pragma unroll 8
    for (int k = 0; k < L_ * H_; ++k)
        s = fmaf(comb[k], fpW[k * D_ + t], s);
    float sum = s, ssq = s * s;
#pragma unroll
    for (int mask = 1; mask < 64; mask <<= 1) {
        sum += __shfl_xor(sum, mask);
        ssq += __shfl_xor(ssq, mask);
    }
    __shared__ float r4[4][2];
    int wv = t >> 6;
    if ((t & 63) == 0) { r4[wv][0] = sum; r4[wv][1] = ssq; }
    __syncthreads();
    sum = r4[0][0] + r4[1][0] + r4[2][0] + r4[3][0];
    ssq = r4[0][1] + r4[1][1] + r4[2][1] + r4[3][1];
    float mu = sum * (1.f / D_);
    float var = fmaf(ssq, 1.f / D_, -mu * mu);
    float rstd = rsqrtf(var + EPS_);
    out[t] = fmaf((s - mu) * rstd, fpg[t], fpbe[t]);
}

extern "C" void kernel_launch(void* const* d_in, const int* in_sizes, int n_in,
                              void* d_out, int out_size, void* d_ws, size_t ws_size,
                              hipStream_t stream) {
    const int*   an    = (const int*)d_in[0];
    const float* pos   = (const float*)d_in[1];
    const float* emb   = (const float*)d_in[2];
    const float* deW   = (const float*)d_in[3];
    const float* deb   = (const float*)d_in[4];
    const float* deg   = (const float*)d_in[5];
    const float* debe  = (const float*)d_in[6];
    const float* msgW  = (const float*)d_in[7];
    const float* msgb  = (const float*)d_in[8];
    const float* msgg  = (const float*)d_in[9];
    const float* msgbe = (const float*)d_in[10];
    const float* updW  = (const float*)d_in[11];
    const float* updb  = (const float*)d_in[12];
    const float* updg  = (const float*)d_in[13];
    const float* updbe = (const float*)d_in[14];
    const float* fpW   = (const float*)d_in[15];
    const float* fpb   = (const float*)d_in[16];
    const float* fpg   = (const float*)d_in[17];
    const float* fpbe  = (const float*)d_in[18];
    float* out = (float*)d_out;

    float* ws    = (float*)d_ws;
    float* x     = ws;                 // N*H
    float* preb  = x    + N_ * H_;     // N*H
    float* prj   = preb + N_ * H_;     // N*H
    float* msum  = prj  + N_ * H_;     // N*H
    float* lmean = msum + N_ * H_;     // L*H

    hipMemsetAsync(lmean, 0, L_ * H_ * sizeof(float), stream);
    k_embed<<<N_ * H_ / 256, 256, 0, stream>>>(an, emb, x);
    for (int lvl = 0; lvl < L_; ++lvl) {
        k_gemm_pp<<<N_, 256, 0, stream>>>(x, msgW + lvl * 2 * H_ * H_, msgb + lvl * H_,
                                          preb, prj);
        k_pair<<<N_, 256, 0, stream>>>(pos, preb, prj, deW, deb, deg, debe,
                                       msgg + lvl * H_, msgbe + lvl * H_, msum);
        k_update<<<N_, H_, 0, stream>>>(x, msum, updW + lvl * 2 * H_ * H_, updb + lvl * H_,
                                        updg + lvl * H_, updbe + lvl * H_, x,
                                        lmean + lvl * H_);
    }
    k_final<<<1, D_, 0, stream>>>(lmean, fpW, fpb, fpg, fpbe, out);
}

// Round 3
// 367.610 us; speedup vs baseline: 2.0692x; 1.1959x over previous
//
#include <hip/hip_runtime.h>
#include <math.h>

constexpr int N_ = 1024;
constexpr int H_ = 128;
constexpr int D_ = 256;
constexpr int L_ = 3;
constexpr float EPS_ = 1e-5f;
constexpr float LOG2E_ = 1.44269504f;
constexpr int KLUT_ = 4096;
constexpr float DMAX_ = 40.0f;
constexpr float TSCALE_ = (KLUT_ - 1) / DMAX_;     // d -> table coordinate
constexpr float TMAX_ = (float)(KLUT_ - 1) - 0.001f;

__device__ __forceinline__ float fsig(float v) {            // sigmoid(v), ~1ulp
    float e = __builtin_amdgcn_exp2f(v * -LOG2E_);
    return __builtin_amdgcn_rcpf(1.0f + e);
}

// butterfly-equivalent reduction over each 16-lane row via DPP row_ror
template <int CTRL>
__device__ __forceinline__ float rowadd(float x) {
    int y = __builtin_amdgcn_update_dpp(0, __float_as_int(x), CTRL, 0xF, 0xF, true);
    return x + __int_as_float(y);
}
__device__ __forceinline__ float rowreduce16(float x) {
    x = rowadd<0x128>(x);   // row_ror:8
    x = rowadd<0x124>(x);   // row_ror:4
    x = rowadd<0x122>(x);   // row_ror:2
    x = rowadd<0x121>(x);   // row_ror:1
    return x;
}

#define LD8(dst, src)                                                     \
    {                                                                     \
        float4 t0_ = *(const float4*)(src);                               \
        float4 t1_ = *(const float4*)((src) + 4);                         \
        dst[0] = t0_.x; dst[1] = t0_.y; dst[2] = t0_.z; dst[3] = t0_.w;   \
        dst[4] = t1_.x; dst[5] = t1_.y; dst[6] = t1_.z; dst[7] = t1_.w;   \
    }

// ---------------- build ew LUT: lut[e][c] = LN(silu(scales(d_e)@deW+deb))*deg+debe ----
// one wave per d-entry; lane owns channels {lane, lane+64}; precise math (one-shot).
__global__ void k_lut(const float* __restrict__ deW, const float* __restrict__ deb,
                      const float* __restrict__ deg, const float* __restrict__ debe,
                      float* __restrict__ lut) {
    int e = blockIdx.x * 4 + (threadIdx.x >> 6);
    int lane = threadIdx.x & 63;
    float d = e * (DMAX_ / (KLUT_ - 1));
    float s0 = expf(-d), s1 = expf(-0.5f * d), s2 = expf(-0.25f * d);
    float v[2];
    float sum = 0.f, ssq = 0.f;
#pragma unroll
    for (int kk = 0; kk < 2; ++kk) {
        int c = lane + 64 * kk;
        float a = s0 * deW[c] + s1 * deW[H_ + c] + s2 * deW[2 * H_ + c] + deb[c];
        float sg = 1.f / (1.f + expf(-a));
        v[kk] = a * sg;
        sum += v[kk]; ssq += v[kk] * v[kk];
    }
#pragma unroll
    for (int mask = 1; mask < 64; mask <<= 1) {
        sum += __shfl_xor(sum, mask);
        ssq += __shfl_xor(ssq, mask);
    }
    float mu = sum * (1.f / H_);
    float var = ssq * (1.f / H_) - mu * mu;
    float rstd = 1.f / sqrtf(var + EPS_);
#pragma unroll
    for (int kk = 0; kk < 2; ++kk) {
        int c = lane + 64 * kk;
        lut[e * H_ + c] = (v[kk] - mu) * rstd * deg[c] + debe[c];
    }
}

// ---------------- x = emb[an]; pre = x@Wi + msg_b; prj = x@Wj ----------------
__global__ void k_embed_gemm(const int* __restrict__ an, const float* __restrict__ emb,
                             const float* __restrict__ W, const float* __restrict__ b,
                             float* __restrict__ x, float* __restrict__ preb,
                             float* __restrict__ prj) {
    int i = blockIdx.x;
    int t = threadIdx.x;               // 256 threads
    __shared__ float xr[H_];
    if (t < H_) {
        float xv = emb[an[i] * H_ + t];
        xr[t] = xv;
        x[i * H_ + t] = xv;
    }
    __syncthreads();
    int h = t & (H_ - 1);
    int off = (t >= H_) ? H_ : 0;
    float s = 0.f;
#pragma unroll 4
    for (int k = 0; k < H_; k += 4) {
        float4 xv = *(const float4*)&xr[k];
        s = fmaf(xv.x, W[(off + k) * H_ + h], s);
        s = fmaf(xv.y, W[(off + k + 1) * H_ + h], s);
        s = fmaf(xv.z, W[(off + k + 2) * H_ + h], s);
        s = fmaf(xv.w, W[(off + k + 3) * H_ + h], s);
    }
    if (t >= H_) prj[i * H_ + h] = s;
    else         preb[i * H_ + h] = s + b[h];
}

// ---------------- the big pairwise kernel (ew via LUT lerp) ----------------
// block = row i, 256 threads = 4 waves; each 16-lane row owns one pair (i,j);
// lane q (0..15 in row) owns 8 contiguous channels [8q, 8q+8).
__global__ __launch_bounds__(256, 4) void k_pair(
    const float* __restrict__ pos, const float* __restrict__ preb,
    const float* __restrict__ prj, const float* __restrict__ lut,
    const float* __restrict__ mgp, const float* __restrict__ mbep,
    float* __restrict__ msum) {
    const int i = blockIdx.x;
    const int tid = threadIdx.x;
    const int w = tid >> 6;
    const int lane = tid & 63;
    const int g = lane >> 4;
    const int q = lane & 15;
    const int p = w * 4 + g;           // 0..15: pair slot within block
    const int cb = q * 8;              // channel base

    __shared__ float dloc[N_];         // table coordinate per j

    float pbv[8], mgv[8], mbev[8], acc[8];
    LD8(pbv, preb + i * H_ + cb);
    LD8(mgv, mgp + cb);
    LD8(mbev, mbep + cb);
#pragma unroll
    for (int k = 0; k < 8; ++k) acc[k] = 0.f;

    const float pix = pos[3 * i], piy = pos[3 * i + 1], piz = pos[3 * i + 2];
    for (int j = tid; j < N_; j += 256) {
        float dx = pix - pos[3 * j];
        float dy = piy - pos[3 * j + 1];
        float dz = piz - pos[3 * j + 2];
        float sq = fmaf(dx, dx, fmaf(dy, dy, dz * dz));
        float d = __builtin_amdgcn_sqrtf(sq);
        dloc[j] = fminf(d * TSCALE_, TMAX_);
    }
    __syncthreads();

    for (int jt = 0; jt < N_; jt += 16) {
        const int j = jt + p;
        float tf = dloc[j];            // broadcast within 16-lane row
        int i0 = (int)tf;
        float fr = tf - (float)i0;
        const float* lp = lut + i0 * H_ + cb;
        float lo[8], hi[8], tm[8];
        LD8(lo, lp);
        LD8(hi, lp + H_);
        LD8(tm, prj + j * H_ + cb);

        float sum = 0.f, ssq = 0.f;
#pragma unroll
        for (int k = 0; k < 8; ++k) {
            float v = pbv[k] + tm[k];
            v *= fsig(v);
            tm[k] = v; sum += v; ssq = fmaf(v, v, ssq);
        }
        sum = rowreduce16(sum);
        ssq = rowreduce16(ssq);
        float mu = sum * (1.f / H_);
        float var = fmaf(ssq, 1.f / H_, -mu * mu);
        float rstd = __builtin_amdgcn_rsqf(var + EPS_);
        float c1 = -mu * rstd;
#pragma unroll
        for (int k = 0; k < 8; ++k) {
            float ew = fmaf(fr, hi[k] - lo[k], lo[k]);
            acc[k] = fmaf(fmaf(fmaf(tm[k], rstd, c1), mgv[k], mbev[k]), ew, acc[k]);
        }
    }

    // ---- combine the 16 pair-slots' partial sums ----
    __shared__ float red[16][H_];
    *(float4*)&red[p][cb] = make_float4(acc[0], acc[1], acc[2], acc[3]);
    *(float4*)&red[p][cb + 4] = make_float4(acc[4], acc[5], acc[6], acc[7]);
    __syncthreads();
    if (tid < H_) {
        float s = 0.f;
#pragma unroll
        for (int pp = 0; pp < 16; ++pp) s += red[pp][tid];
        msum[i * H_ + tid] = s;
    }
}

// ---- x += LN(silu([x,msum]@uW+ub)); lmean += x; then pre/prj for next level ----
__global__ void k_upd_gemm(const float* __restrict__ x_in, const float* __restrict__ msum,
                           const float* __restrict__ uW, const float* __restrict__ ub,
                           const float* __restrict__ ug, const float* __restrict__ ube,
                           const float* __restrict__ Wn, const float* __restrict__ bn,
                           float* __restrict__ x_out, float* __restrict__ lmean,
                           float* __restrict__ preb, float* __restrict__ prj) {
    int i = blockIdx.x;
    int t = threadIdx.x;               // 256 threads
    int h = t & (H_ - 1);
    int half = t >> 7;
    __shared__ float u[2 * H_];
    __shared__ float part[2][H_];
    __shared__ float xs[H_];
    __shared__ float r4[4][2];
    if (t < H_) u[t] = x_in[i * H_ + t];
    else        u[t] = msum[i * H_ + h];
    __syncthreads();
    // u @ uW, split K across the two thread-halves
    float s = 0.f;
    const int kb = half * H_;
#pragma unroll 4
    for (int k = 0; k < H_; k += 4) {
        float4 uv = *(const float4*)&u[kb + k];
        s = fmaf(uv.x, uW[(kb + k) * H_ + h], s);
        s = fmaf(uv.y, uW[(kb + k + 1) * H_ + h], s);
        s = fmaf(uv.z, uW[(kb + k + 2) * H_ + h], s);
        s = fmaf(uv.w, uW[(kb + k + 3) * H_ + h], s);
    }
    part[half][h] = s;
    __syncthreads();
    float v = 0.f;
    if (t < H_) {
        float sv = part[0][t] + part[1][t] + ub[t];
        v = sv * fsig(sv);
    }
    float sum = v, ssq = v * v;
#pragma unroll
    for (int mask = 1; mask < 64; mask <<= 1) {
        sum += __shfl_xor(sum, mask);
        ssq += __shfl_xor(ssq, mask);
    }
    if ((t & 63) == 0) { r4[t >> 6][0] = sum; r4[t >> 6][1] = ssq; }
    __syncthreads();
    if (t < H_) {
        sum = r4[0][0] + r4[1][0];
        ssq = r4[0][1] + r4[1][1];
        float mu = sum * (1.f / H_);
        float var = fmaf(ssq, 1.f / H_, -mu * mu);
        float rstd = rsqrtf(var + EPS_);
        float xn = u[t] + fmaf((v - mu) * rstd, ug[t], ube[t]);
        xs[t] = xn;
        x_out[i * H_ + t] = xn;
        atomicAdd(&lmean[t], xn);
    }
    if (Wn) {
        __syncthreads();
        int off = (t >= H_) ? H_ : 0;
        float s2 = 0.f;
#pragma unroll 4
        for (int k = 0; k < H_; k += 4) {
            float4 xv = *(const float4*)&xs[k];
            s2 = fmaf(xv.x, Wn[(off + k) * H_ + h], s2);
            s2 = fmaf(xv.y, Wn[(off + k + 1) * H_ + h], s2);
            s2 = fmaf(xv.z, Wn[(off + k + 2) * H_ + h], s2);
            s2 = fmaf(xv.w, Wn[(off + k + 3) * H_ + h], s2);
        }
        if (t >= H_) prj[i * H_ + h] = s2;
        else         preb[i * H_ + h] = s2 + bn[h];
    }
}

// ---------------- out = LN(combined @ fp_W + fp_b) ----------------
__global__ void k_final(const float* __restrict__ lmean, const float* __restrict__ fpW,
                        const float* __restrict__ fpb, const float* __restrict__ fpg,
                        const float* __restrict__ fpbe, float* __restrict__ out) {
    int t = threadIdx.x;               // 256 threads
    __shared__ float comb[L_ * H_];    // 384
    comb[t] = lmean[t] * (1.f / N_);
    if (t < L_ * H_ - D_) comb[D_ + t] = lmean[D_ + t] * (1.f / N_);
    __syncthreads();
    float s = fpb[t];
#pragma unroll 8
    for (int k = 0; k < L_ * H_; ++k)
        s = fmaf(comb[k], fpW[k * D_ + t], s);
    float sum = s, ssq = s * s;
#pragma unroll
    for (int mask = 1; mask < 64; mask <<= 1) {
        sum += __shfl_xor(sum, mask);
        ssq += __shfl_xor(ssq, mask);
    }
    __shared__ float r4[4][2];
    int wv = t >> 6;
    if ((t & 63) == 0) { r4[wv][0] = sum; r4[wv][1] = ssq; }
    __syncthreads();
    sum = r4[0][0] + r4[1][0] + r4[2][0] + r4[3][0];
    ssq = r4[0][1] + r4[1][1] + r4[2][1] + r4[3][1];
    float mu = sum * (1.f / D_);
    float var = fmaf(ssq, 1.f / D_, -mu * mu);
    float rstd = rsqrtf(var + EPS_);
    out[t] = fmaf((s - mu) * rstd, fpg[t], fpbe[t]);
}

extern "C" void kernel_launch(void* const* d_in, const int* in_sizes, int n_in,
                              void* d_out, int out_size, void* d_ws, size_t ws_size,
                              hipStream_t stream) {
    const int*   an    = (const int*)d_in[0];
    const float* pos   = (const float*)d_in[1];
    const float* emb   = (const float*)d_in[2];
    const float* deW   = (const float*)d_in[3];
    const float* deb   = (const float*)d_in[4];
    const float* deg   = (const float*)d_in[5];
    const float* debe  = (const float*)d_in[6];
    const float* msgW  = (const float*)d_in[7];
    const float* msgb  = (const float*)d_in[8];
    const float* msgg  = (const float*)d_in[9];
    const float* msgbe = (const float*)d_in[10];
    const float* updW  = (const float*)d_in[11];
    const float* updb  = (const float*)d_in[12];
    const float* updg  = (const float*)d_in[13];
    const float* updbe = (const float*)d_in[14];
    const float* fpW   = (const float*)d_in[15];
    const float* fpb   = (const float*)d_in[16];
    const float* fpg   = (const float*)d_in[17];
    const float* fpbe  = (const float*)d_in[18];
    float* out = (float*)d_out;

    float* ws    = (float*)d_ws;
    float* x     = ws;                 // N*H
    float* preb  = x    + N_ * H_;     // N*H
    float* prj   = preb + N_ * H_;     // N*H
    float* msum  = prj  + N_ * H_;     // N*H
    float* lmean = msum + N_ * H_;     // L*H
    float* lut   = lmean + L_ * H_;    // KLUT*H (2 MB)

    hipMemsetAsync(lmean, 0, L_ * H_ * sizeof(float), stream);
    k_lut<<<KLUT_ / 4, 256, 0, stream>>>(deW, deb, deg, debe, lut);
    k_embed_gemm<<<N_, 256, 0, stream>>>(an, emb, msgW, msgb, x, preb, prj);
    for (int lvl = 0; lvl < L_; ++lvl) {
        k_pair<<<N_, 256, 0, stream>>>(pos, preb, prj, lut,
                                       msgg + lvl * H_, msgbe + lvl * H_, msum);
        const float* Wn = (lvl < L_ - 1) ? msgW + (lvl + 1) * 2 * H_ * H_ : nullptr;
        const float* bn = (lvl < L_ - 1) ? msgb + (lvl + 1) * H_ : nullptr;
        k_upd_gemm<<<N_, 256, 0, stream>>>(x, msum, updW + lvl * 2 * H_ * H_,
                                           updb + lvl * H_, updg + lvl * H_,
                                           updbe + lvl * H_, Wn, bn, x,
                                           lmean + lvl * H_, preb, prj);
    }
    k_final<<<1, D_, 0, stream>>>(lmean, fpW, fpb, fpg, fpbe, out);
}